// Round 6
// baseline (171.739 us; speedup 1.0000x reference)
//
#include <hip/hip_runtime.h>
#include <math.h>

// (B,P,V,F,H) = (32,512,32,16,64). Round 6: round-5 design + LDS halved.
// One wave = one bp. Weights pre-packed by a pre-pass kernel into bf16 MFMA
// B-fragment order in d_ws (36 KB, L1/L2-resident); main kernel fetches each
// frag as one global_load_dwordx4 on the VMEM pipe (keeps VGPRs at ~60).
// KEY CHANGE vs round 5: the layer-2 and layer-3 x-buffers/pool arrays ALIAS
// (DS pipe is in-order within a wave: layerK's ds_reads are issued before the
// next epilogue's ds_writes, so WAR is safe). LDS 37.9 -> 18.9 KB/block =>
// 8 blocks/CU; __launch_bounds__(256,8) for 8 waves/SIMD (VGPR 60 <= 64).
// MFMA 16x16x32 bf16: A[m=lane&15][k=quad*8+j], B[k=quad*8+j][n=lane&15],
//                     D[row=quad*4+reg][col=lane&15]  (verified rounds 2-5).
namespace {
constexpr int kXS = 72;
constexpr float kSlope = 0.01f;

typedef short bf16x8 __attribute__((ext_vector_type(8)));
typedef float f32x4  __attribute__((ext_vector_type(4)));

__device__ __forceinline__ float lrelu(float x) { return fmaxf(x, kSlope * x); }

// round-to-nearest-even f32->bf16, branch-free (inputs finite here).
__device__ __forceinline__ unsigned short bfrne(float a) {
    union { float f; unsigned u; } v; v.f = a;
    return (unsigned short)((v.u + 0x7FFFu + ((v.u >> 16) & 1u)) >> 16);
}

// ---- pre-pass: pack W1/W2/W3 as bf16 MFMA B-frags into d_ws ----
// frag f: 0..3 = W1 (nt=f, K=16 zero-padded); 4..19 = W2 (nt=(f-4)>>2,
// ks=(f-4)&3); 20..35 = W3. Lane l of frag f lives at ws[f*512 + l*8 ..+7].
__global__ void prep_weights(const float* __restrict__ W1,
                             const float* __restrict__ W2,
                             const float* __restrict__ W3,
                             unsigned short* __restrict__ ws)
{
    int t = blockIdx.x * blockDim.x + threadIdx.x;
    if (t >= 36 * 64) return;
    int f = t >> 6, l = t & 63, c = l & 15, q = l >> 4;
    unsigned short v[8] = {0, 0, 0, 0, 0, 0, 0, 0};
    const float* src = nullptr; int row = 0, k0 = 0, K = 0;
    if (f < 4) {
        if (q < 2) { src = W1; row = 16 * f + c; k0 = q * 8; K = 16; }
    } else if (f < 20) {
        int g = f - 4;  src = W2; row = 16 * (g >> 2) + c; k0 = (g & 3) * 32 + q * 8; K = 128;
    } else {
        int g = f - 20; src = W3; row = 16 * (g >> 2) + c; k0 = (g & 3) * 32 + q * 8; K = 128;
    }
    if (src) {
        #pragma unroll
        for (int j = 0; j < 8; ++j) v[j] = bfrne(src[row * K + k0 + j]);
    }
    unsigned short* dst = ws + (size_t)f * 512 + l * 8;
    *(ushort4*)(dst)     = make_ushort4(v[0], v[1], v[2], v[3]);
    *(ushort4*)(dst + 4) = make_ushort4(v[4], v[5], v[6], v[7]);
}

__global__ __launch_bounds__(256, 8) void fused_mlp_v6(
    const float* __restrict__ X, const int* __restrict__ M,
    const unsigned short* __restrict__ WF,
    const float* __restrict__ B1, const float* __restrict__ B2,
    const float* __restrict__ B3, float* __restrict__ OUT)
{
    __shared__ __align__(16) short sX[4][32 * kXS];  // 18432 B (single buffer!)
    __shared__ __align__(16) short sP[4][64];        //   512 B

    const int t = threadIdx.x, w = t >> 6, l = t & 63, c = l & 15, q = l >> 4;
    const size_t bp = (size_t)blockIdx.x * 4 + w;

    short* xb = &sX[w][0];   // shared by layer-2 and layer-3 stages (in-order DS)
    short* pl = &sP[w][0];

    // ---- inputs for this bp ----
    float4 xr[2][2];
    if (q < 2) {
        #pragma unroll
        for (int mt = 0; mt < 2; ++mt) {
            const float4* p = (const float4*)(X + (bp * 32 + 16 * mt + c) * 16 + q * 8);
            xr[mt][0] = p[0]; xr[mt][1] = p[1];
        }
    }
    const int4* Mp = (const int4*)(M + bp * 32);
    const int4 mr0 = Mp[q], mr1 = Mp[4 + q];
    const unsigned mbits =
        (mr0.x ? 1u : 0u)  | (mr0.y ? 2u : 0u)  | (mr0.z ? 4u : 0u)  | (mr0.w ? 8u : 0u) |
        (mr1.x ? 16u : 0u) | (mr1.y ? 32u : 0u) | (mr1.z ? 64u : 0u) | (mr1.w ? 128u : 0u);
    const bool anyv = __any(mbits != 0);

    float bias1[4], bias2[4], bias3[4];
    #pragma unroll
    for (int nt = 0; nt < 4; ++nt) {
        bias1[nt] = B1[16 * nt + c];
        bias2[nt] = B2[16 * nt + c];
        bias3[nt] = B3[16 * nt + c];
    }

    f32x4 acc[2][4];

    // ---- layer 1 (K=16 zero-padded to 32); W1 frags from WF ----
    {
        bf16x8 a1f[2];
        #pragma unroll
        for (int mt = 0; mt < 2; ++mt) {
            bf16x8 v = {};
            if (q < 2) {
                float4 f0 = xr[mt][0], f1 = xr[mt][1];
                v[0] = (short)bfrne(f0.x); v[1] = (short)bfrne(f0.y);
                v[2] = (short)bfrne(f0.z); v[3] = (short)bfrne(f0.w);
                v[4] = (short)bfrne(f1.x); v[5] = (short)bfrne(f1.y);
                v[6] = (short)bfrne(f1.z); v[7] = (short)bfrne(f1.w);
            }
            a1f[mt] = v;
        }
        #pragma unroll
        for (int nt = 0; nt < 4; ++nt) {
            bf16x8 wf = *(const bf16x8*)(WF + (size_t)nt * 512 + l * 8);
            f32x4 c0 = { bias1[nt], bias1[nt], bias1[nt], bias1[nt] };
            acc[0][nt] = __builtin_amdgcn_mfma_f32_16x16x32_bf16(a1f[0], wf, c0, 0, 0, 0);
            acc[1][nt] = __builtin_amdgcn_mfma_f32_16x16x32_bf16(a1f[1], wf, c0, 0, 0, 0);
        }
    }

    // ---- epilogue: lrelu/mask, direct b16 writes (imm offsets), pool array ----
    auto epilogue = [&]() {
        float pool[4];
        #pragma unroll
        for (int nt = 0; nt < 4; ++nt) {
            float pv = -INFINITY;
            #pragma unroll
            for (int mt = 0; mt < 2; ++mt) {
                short* base = &xb[(16 * mt + 4 * q) * kXS + 16 * nt + c];
                #pragma unroll
                for (int r = 0; r < 4; ++r) {
                    float y = lrelu(acc[mt][nt][r]);
                    bool mk = (mbits >> (mt * 4 + r)) & 1;
                    float o = mk ? y : 0.f;
                    pv = mk ? fmaxf(pv, y) : pv;
                    base[r * kXS] = (short)bfrne(o);
                }
            }
            pv = fmaxf(pv, __shfl_xor(pv, 16));
            pv = fmaxf(pv, __shfl_xor(pv, 32));
            pool[nt] = anyv ? pv : 0.f;
        }
        float ps = (q & 2) ? ((q & 1) ? pool[3] : pool[2])
                           : ((q & 1) ? pool[1] : pool[0]);
        pl[16 * q + c] = (short)bfrne(ps);
    };

    // ---- K=128 layer: A-frags from LDS, W-frags streamed from WF (VMEM) ----
    auto layerK = [&](int fb, const float (&bias)[4]) {
        bf16x8 a00 = *(const bf16x8*)&xb[(     c) * kXS      + q * 8];
        bf16x8 a01 = *(const bf16x8*)&xb[(16 + c) * kXS      + q * 8];
        bf16x8 a10 = *(const bf16x8*)&xb[(     c) * kXS + 32 + q * 8];
        bf16x8 a11 = *(const bf16x8*)&xb[(16 + c) * kXS + 32 + q * 8];
        bf16x8 ap0 = *(const bf16x8*)&pl[q * 8];        // quad-broadcast
        bf16x8 ap1 = *(const bf16x8*)&pl[32 + q * 8];
        #pragma unroll
        for (int nt = 0; nt < 4; ++nt) {
            acc[0][nt] = f32x4{ bias[nt], bias[nt], bias[nt], bias[nt] };
            acc[1][nt] = acc[0][nt];
        }
        #pragma unroll
        for (int ks = 0; ks < 4; ++ks) {
            bf16x8 am0 = (ks == 0) ? a00 : (ks == 1) ? a10 : (ks == 2) ? ap0 : ap1;
            bf16x8 am1 = (ks == 0) ? a01 : (ks == 1) ? a11 : (ks == 2) ? ap0 : ap1;
            #pragma unroll
            for (int nt = 0; nt < 4; ++nt) {
                bf16x8 wf = *(const bf16x8*)(WF + ((size_t)(fb + nt * 4 + ks)) * 512 + l * 8);
                acc[0][nt] = __builtin_amdgcn_mfma_f32_16x16x32_bf16(am0, wf, acc[0][nt], 0, 0, 0);
                acc[1][nt] = __builtin_amdgcn_mfma_f32_16x16x32_bf16(am1, wf, acc[1][nt], 0, 0, 0);
            }
        }
    };

    epilogue();            // x2 = [out1 | pool1]
    layerK(4, bias2);      // layer 2 (reads xb/pl before any new writes)
    epilogue();            // x3 overwrites x2 in-place (safe: in-order DS)
    layerK(20, bias3);     // layer 3

    // ---- layer-3 pool == final output ----
    {
        float pool[4];
        #pragma unroll
        for (int nt = 0; nt < 4; ++nt) {
            float pv = -INFINITY;
            #pragma unroll
            for (int mt = 0; mt < 2; ++mt)
                #pragma unroll
                for (int r = 0; r < 4; ++r) {
                    bool mk = (mbits >> (mt * 4 + r)) & 1;
                    float y = lrelu(acc[mt][nt][r]);
                    pv = mk ? fmaxf(pv, y) : pv;
                }
            pv = fmaxf(pv, __shfl_xor(pv, 16));
            pv = fmaxf(pv, __shfl_xor(pv, 32));
            pool[nt] = anyv ? pv : 0.f;
        }
        float ps = (q & 2) ? ((q & 1) ? pool[3] : pool[2])
                           : ((q & 1) ? pool[1] : pool[0]);
        OUT[bp * 64 + 16 * q + c] = ps;
    }
}
} // namespace

extern "C" void kernel_launch(void* const* d_in, const int* in_sizes, int n_in,
                              void* d_out, int out_size, void* d_ws, size_t ws_size,
                              hipStream_t stream) {
    (void)in_sizes; (void)n_in; (void)ws_size; (void)out_size;
    const float* X  = (const float*)d_in[0];
    const int*   M  = (const int*)d_in[1];
    const float* W1 = (const float*)d_in[2];
    const float* B1 = (const float*)d_in[3];
    const float* W2 = (const float*)d_in[4];
    const float* B2 = (const float*)d_in[5];
    const float* W3 = (const float*)d_in[6];
    const float* B3 = (const float*)d_in[7];
    float* OUT = (float*)d_out;
    unsigned short* WF = (unsigned short*)d_ws;   // needs 36 KB of scratch

    prep_weights<<<(36 * 64 + 255) / 256, 256, 0, stream>>>(W1, W2, W3, WF);
    // 4096 blocks x 4 waves = 16384 waves; one bp per wave
    fused_mlp_v6<<<4096, 256, 0, stream>>>(X, M, WF, B1, B2, B3, OUT);
}

// Round 7
// 119.972 us; speedup vs baseline: 1.4315x; 1.4315x over previous
//
#include <hip/hip_runtime.h>
#include <math.h>

// (B,P,V,F,H) = (32,512,32,16,64). Round 7 = round 6 with the spill fixed.
// One wave = one bp. Weights pre-packed into bf16 MFMA B-frag order in d_ws
// (36 KB, L1/L2-resident), fetched as global_load_dwordx4 on the VMEM pipe.
// Layer-2/3 x-buffers ALIAS (in-order DS within a wave => WAR-safe): LDS
// 18.9 KB/block. __launch_bounds__(256,4): round-6's (256,8) capped the
// UNIFIED reg file at 64/wave while the true working set is ~95 (arch ~60 +
// 32 acc in the unified AGPR half) -> 164 MB scratch spill. (256,4) caps at
// 128 => no spill; runtime occupancy is set by actual alloc (~96 regs ->
// 5 waves/SIMD) and LDS (8 blocks/CU), not by the bound.
// MFMA 16x16x32 bf16: A[m=lane&15][k=quad*8+j], B[k=quad*8+j][n=lane&15],
//                     D[row=quad*4+reg][col=lane&15]  (verified rounds 2-6).
namespace {
constexpr int kXS = 72;
constexpr float kSlope = 0.01f;

typedef short bf16x8 __attribute__((ext_vector_type(8)));
typedef float f32x4  __attribute__((ext_vector_type(4)));

__device__ __forceinline__ float lrelu(float x) { return fmaxf(x, kSlope * x); }

// round-to-nearest-even f32->bf16, branch-free (inputs finite here).
__device__ __forceinline__ unsigned short bfrne(float a) {
    union { float f; unsigned u; } v; v.f = a;
    return (unsigned short)((v.u + 0x7FFFu + ((v.u >> 16) & 1u)) >> 16);
}

// ---- pre-pass: pack W1/W2/W3 as bf16 MFMA B-frags into d_ws ----
// frag f: 0..3 = W1 (nt=f, K=16 zero-padded); 4..19 = W2 (nt=(f-4)>>2,
// ks=(f-4)&3); 20..35 = W3. Lane l of frag f lives at ws[f*512 + l*8 ..+7].
__global__ void prep_weights(const float* __restrict__ W1,
                             const float* __restrict__ W2,
                             const float* __restrict__ W3,
                             unsigned short* __restrict__ ws)
{
    int t = blockIdx.x * blockDim.x + threadIdx.x;
    if (t >= 36 * 64) return;
    int f = t >> 6, l = t & 63, c = l & 15, q = l >> 4;
    unsigned short v[8] = {0, 0, 0, 0, 0, 0, 0, 0};
    const float* src = nullptr; int row = 0, k0 = 0, K = 0;
    if (f < 4) {
        if (q < 2) { src = W1; row = 16 * f + c; k0 = q * 8; K = 16; }
    } else if (f < 20) {
        int g = f - 4;  src = W2; row = 16 * (g >> 2) + c; k0 = (g & 3) * 32 + q * 8; K = 128;
    } else {
        int g = f - 20; src = W3; row = 16 * (g >> 2) + c; k0 = (g & 3) * 32 + q * 8; K = 128;
    }
    if (src) {
        #pragma unroll
        for (int j = 0; j < 8; ++j) v[j] = bfrne(src[row * K + k0 + j]);
    }
    unsigned short* dst = ws + (size_t)f * 512 + l * 8;
    *(ushort4*)(dst)     = make_ushort4(v[0], v[1], v[2], v[3]);
    *(ushort4*)(dst + 4) = make_ushort4(v[4], v[5], v[6], v[7]);
}

__global__ __launch_bounds__(256, 4) void fused_mlp_v7(
    const float* __restrict__ X, const int* __restrict__ M,
    const unsigned short* __restrict__ WF,
    const float* __restrict__ B1, const float* __restrict__ B2,
    const float* __restrict__ B3, float* __restrict__ OUT)
{
    __shared__ __align__(16) short sX[4][32 * kXS];  // 18432 B (aliased L2/L3 buffer)
    __shared__ __align__(16) short sP[4][64];        //   512 B

    const int t = threadIdx.x, w = t >> 6, l = t & 63, c = l & 15, q = l >> 4;
    const size_t bp = (size_t)blockIdx.x * 4 + w;

    short* xb = &sX[w][0];
    short* pl = &sP[w][0];

    // ---- inputs for this bp ----
    float4 xr[2][2];
    if (q < 2) {
        #pragma unroll
        for (int mt = 0; mt < 2; ++mt) {
            const float4* p = (const float4*)(X + (bp * 32 + 16 * mt + c) * 16 + q * 8);
            xr[mt][0] = p[0]; xr[mt][1] = p[1];
        }
    }
    const int4* Mp = (const int4*)(M + bp * 32);
    const int4 mr0 = Mp[q], mr1 = Mp[4 + q];
    const unsigned mbits =
        (mr0.x ? 1u : 0u)  | (mr0.y ? 2u : 0u)  | (mr0.z ? 4u : 0u)  | (mr0.w ? 8u : 0u) |
        (mr1.x ? 16u : 0u) | (mr1.y ? 32u : 0u) | (mr1.z ? 64u : 0u) | (mr1.w ? 128u : 0u);
    const bool anyv = __any(mbits != 0);

    f32x4 acc[2][4];

    // ---- layer 1 (K=16 zero-padded to 32); W1 frags from WF ----
    {
        bf16x8 a1f[2];
        #pragma unroll
        for (int mt = 0; mt < 2; ++mt) {
            bf16x8 v = {};
            if (q < 2) {
                float4 f0 = xr[mt][0], f1 = xr[mt][1];
                v[0] = (short)bfrne(f0.x); v[1] = (short)bfrne(f0.y);
                v[2] = (short)bfrne(f0.z); v[3] = (short)bfrne(f0.w);
                v[4] = (short)bfrne(f1.x); v[5] = (short)bfrne(f1.y);
                v[6] = (short)bfrne(f1.z); v[7] = (short)bfrne(f1.w);
            }
            a1f[mt] = v;
        }
        #pragma unroll
        for (int nt = 0; nt < 4; ++nt) {
            float b = B1[16 * nt + c];               // transient live range
            bf16x8 wf = *(const bf16x8*)(WF + (size_t)nt * 512 + l * 8);
            f32x4 c0 = { b, b, b, b };
            acc[0][nt] = __builtin_amdgcn_mfma_f32_16x16x32_bf16(a1f[0], wf, c0, 0, 0, 0);
            acc[1][nt] = __builtin_amdgcn_mfma_f32_16x16x32_bf16(a1f[1], wf, c0, 0, 0, 0);
        }
    }

    // ---- epilogue: lrelu/mask, direct b16 writes (imm offsets), pool array ----
    auto epilogue = [&]() {
        float pool[4];
        #pragma unroll
        for (int nt = 0; nt < 4; ++nt) {
            float pv = -INFINITY;
            #pragma unroll
            for (int mt = 0; mt < 2; ++mt) {
                short* base = &xb[(16 * mt + 4 * q) * kXS + 16 * nt + c];
                #pragma unroll
                for (int r = 0; r < 4; ++r) {
                    float y = lrelu(acc[mt][nt][r]);
                    bool mk = (mbits >> (mt * 4 + r)) & 1;
                    float o = mk ? y : 0.f;
                    pv = mk ? fmaxf(pv, y) : pv;
                    base[r * kXS] = (short)bfrne(o);
                }
            }
            pv = fmaxf(pv, __shfl_xor(pv, 16));
            pv = fmaxf(pv, __shfl_xor(pv, 32));
            pool[nt] = anyv ? pv : 0.f;
        }
        float ps = (q & 2) ? ((q & 1) ? pool[3] : pool[2])
                           : ((q & 1) ? pool[1] : pool[0]);
        pl[16 * q + c] = (short)bfrne(ps);
    };

    // ---- K=128 layer: A-frags from LDS, W-frags streamed from WF (VMEM) ----
    auto layerK = [&](int fb, const float* __restrict__ Bv) {
        bf16x8 a00 = *(const bf16x8*)&xb[(     c) * kXS      + q * 8];
        bf16x8 a01 = *(const bf16x8*)&xb[(16 + c) * kXS      + q * 8];
        bf16x8 a10 = *(const bf16x8*)&xb[(     c) * kXS + 32 + q * 8];
        bf16x8 a11 = *(const bf16x8*)&xb[(16 + c) * kXS + 32 + q * 8];
        bf16x8 ap0 = *(const bf16x8*)&pl[q * 8];        // quad-broadcast
        bf16x8 ap1 = *(const bf16x8*)&pl[32 + q * 8];
        #pragma unroll
        for (int nt = 0; nt < 4; ++nt) {
            float b = Bv[16 * nt + c];                   // transient live range
            acc[0][nt] = f32x4{ b, b, b, b };
            acc[1][nt] = acc[0][nt];
        }
        #pragma unroll
        for (int ks = 0; ks < 4; ++ks) {
            bf16x8 am0 = (ks == 0) ? a00 : (ks == 1) ? a10 : (ks == 2) ? ap0 : ap1;
            bf16x8 am1 = (ks == 0) ? a01 : (ks == 1) ? a11 : (ks == 2) ? ap0 : ap1;
            #pragma unroll
            for (int nt = 0; nt < 4; ++nt) {
                bf16x8 wf = *(const bf16x8*)(WF + ((size_t)(fb + nt * 4 + ks)) * 512 + l * 8);
                acc[0][nt] = __builtin_amdgcn_mfma_f32_16x16x32_bf16(am0, wf, acc[0][nt], 0, 0, 0);
                acc[1][nt] = __builtin_amdgcn_mfma_f32_16x16x32_bf16(am1, wf, acc[1][nt], 0, 0, 0);
            }
        }
    };

    epilogue();            // x2 = [out1 | pool1]
    layerK(4, B2);         // layer 2 (reads xb/pl before any new writes)
    epilogue();            // x3 overwrites x2 in-place (safe: in-order DS)
    layerK(20, B3);        // layer 3

    // ---- layer-3 pool == final output ----
    {
        float pool[4];
        #pragma unroll
        for (int nt = 0; nt < 4; ++nt) {
            float pv = -INFINITY;
            #pragma unroll
            for (int mt = 0; mt < 2; ++mt)
                #pragma unroll
                for (int r = 0; r < 4; ++r) {
                    bool mk = (mbits >> (mt * 4 + r)) & 1;
                    float y = lrelu(acc[mt][nt][r]);
                    pv = mk ? fmaxf(pv, y) : pv;
                }
            pv = fmaxf(pv, __shfl_xor(pv, 16));
            pv = fmaxf(pv, __shfl_xor(pv, 32));
            pool[nt] = anyv ? pv : 0.f;
        }
        float ps = (q & 2) ? ((q & 1) ? pool[3] : pool[2])
                           : ((q & 1) ? pool[1] : pool[0]);
        OUT[bp * 64 + 16 * q + c] = ps;
    }
}
} // namespace

extern "C" void kernel_launch(void* const* d_in, const int* in_sizes, int n_in,
                              void* d_out, int out_size, void* d_ws, size_t ws_size,
                              hipStream_t stream) {
    (void)in_sizes; (void)n_in; (void)ws_size; (void)out_size;
    const float* X  = (const float*)d_in[0];
    const int*   M  = (const int*)d_in[1];
    const float* W1 = (const float*)d_in[2];
    const float* B1 = (const float*)d_in[3];
    const float* W2 = (const float*)d_in[4];
    const float* B2 = (const float*)d_in[5];
    const float* W3 = (const float*)d_in[6];
    const float* B3 = (const float*)d_in[7];
    float* OUT = (float*)d_out;
    unsigned short* WF = (unsigned short*)d_ws;   // needs 36 KB of scratch

    prep_weights<<<(36 * 64 + 255) / 256, 256, 0, stream>>>(W1, W2, W3, WF);
    // 4096 blocks x 4 waves = 16384 waves; one bp per wave
    fused_mlp_v7<<<4096, 256, 0, stream>>>(X, M, WF, B1, B2, B3, OUT);
}